// Round 10
// baseline (173.305 us; speedup 1.0000x reference)
//
#include <hip/hip_runtime.h>
#include <math.h>

#define NUM_TOKENS 16384
#define HIDDEN 2048
#define NUM_EXPERTS 64

// out layout (fp32 flat): [0,32768) weights [t][2]; [32768,65536) indices as float; [65536] aux
#define IDX_OFF 32768
#define AUX_OFF 65536

#define TPB 8                        // tokens per block
#define NBLK (NUM_TOKENS / TPB)      // 2048 blocks
#define KSL (HIDDEN / 8)             // 256 k per wave (8 waves = 8 k-slices)
#define NCK (KSL / 16)               // 16 chunks of 16 k

typedef float v2f __attribute__((ext_vector_type(2)));

// No barriers, no LDS, no inline asm in the k-loop. 8 waves/block each own a
// 256-k slice of the block's 8 tokens; lane = (phase = lane>>4, eq = lane&15).
// All operands are plain per-lane vector loads -> compiler pipelines them and
// inserts counted vmcnts itself. Grid 2048 -> ~6 independent waves/SIMD.
__global__ __launch_bounds__(512, 4) void router_kernel(
    const float* __restrict__ x, const float* __restrict__ Wg,
    float* __restrict__ out, float* __restrict__ ws)
{
    __shared__ float red[8][TPB][68];    // k-slice partials (17.4 KB)

    const int tid  = threadIdx.x;
    const int w    = __builtin_amdgcn_readfirstlane(tid >> 6);  // k-slice 0..7
    const int lane = tid & 63;
    const int ph   = lane >> 4;          // k-phase 0..3
    const int eq   = lane & 15;          // expert quad
    const int tok0 = blockIdx.x * TPB;
    const int k0   = w * KSL;

    v2f C2[TPB][2];
    #pragma unroll
    for (int t = 0; t < TPB; ++t) { C2[t][0] = (v2f)(0.f); C2[t][1] = (v2f)(0.f); }

    const float* xb = x  + (size_t)tok0 * HIDDEN + k0 + ph * 4;   // per-lane base
    const float* wb = Wg + (size_t)k0 * NUM_EXPERTS + eq * 4;     // per-lane base

    for (int ck = 0; ck < NCK; ++ck) {
        // x: one float4 per token (4 k of this lane's phase); 4 distinct addrs/instr
        float4 xv[TPB];
        #pragma unroll
        for (int t = 0; t < TPB; ++t)
            xv[t] = *reinterpret_cast<const float4*>(
                xb + (size_t)t * HIDDEN + ck * 16);
        // W: 4 rows (this phase's k), 4 experts each; 256B-contiguous per row
        float4 wv[4];
        #pragma unroll
        for (int jj = 0; jj < 4; ++jj)
            wv[jj] = *reinterpret_cast<const float4*>(
                wb + (size_t)(ck * 16 + ph * 4 + jj) * NUM_EXPERTS);
        // 64 packed FMA
        #pragma unroll
        for (int t = 0; t < TPB; ++t) {
            const float xs[4] = {xv[t].x, xv[t].y, xv[t].z, xv[t].w};
            #pragma unroll
            for (int jj = 0; jj < 4; ++jj) {
                const v2f a = (v2f){xs[jj], xs[jj]};
                C2[t][0] = __builtin_elementwise_fma(a, (v2f){wv[jj].x, wv[jj].y}, C2[t][0]);
                C2[t][1] = __builtin_elementwise_fma(a, (v2f){wv[jj].z, wv[jj].w}, C2[t][1]);
            }
        }
    }

    // phase merge: sum the 4 k-phases (lanes differing in bits 4/5, eq constant)
    float Cf[TPB][4];
    #pragma unroll
    for (int t = 0; t < TPB; ++t) {
        Cf[t][0] = C2[t][0].x; Cf[t][1] = C2[t][0].y;
        Cf[t][2] = C2[t][1].x; Cf[t][3] = C2[t][1].y;
        #pragma unroll
        for (int j = 0; j < 4; ++j) {
            float v = Cf[t][j];
            v += __shfl_xor(v, 16);
            v += __shfl_xor(v, 32);
            Cf[t][j] = v;
        }
    }

    // k-slice partials -> LDS
    if (ph == 0) {
        #pragma unroll
        for (int t = 0; t < TPB; ++t) {
            float4 v; v.x = Cf[t][0]; v.y = Cf[t][1]; v.z = Cf[t][2]; v.w = Cf[t][3];
            *reinterpret_cast<float4*>(&red[w][t][eq * 4]) = v;
        }
    }
    __syncthreads();

    // wave 0: sum 8 slices, softmax + top-2 per token (lane = expert)
    if (w == 0) {
        float accP = 0.f, accC = 0.f;
        #pragma unroll
        for (int t = 0; t < TPB; ++t) {
            float l = 0.f;
            #pragma unroll
            for (int s = 0; s < 8; ++s) l += red[s][t][lane];

            float m = l;
            #pragma unroll
            for (int off = 32; off >= 1; off >>= 1) m = fmaxf(m, __shfl_xor(m, off));
            const float p = expf(l - m);
            float Z = p;
            #pragma unroll
            for (int off = 32; off >= 1; off >>= 1) Z += __shfl_xor(Z, off);
            const float prob = p / Z;

            float v1 = prob; int i1 = lane;
            #pragma unroll
            for (int off = 32; off >= 1; off >>= 1) {
                const float ov = __shfl_xor(v1, off);
                const int   oi = __shfl_xor(i1, off);
                if (ov > v1 || (ov == v1 && oi < i1)) { v1 = ov; i1 = oi; }
            }
            float v2 = (lane == i1) ? -1.f : prob; int i2 = lane;
            #pragma unroll
            for (int off = 32; off >= 1; off >>= 1) {
                const float ov = __shfl_xor(v2, off);
                const int   oi = __shfl_xor(i2, off);
                if (ov > v2 || (ov == v2 && oi < i2)) { v2 = ov; i2 = oi; }
            }

            accP += prob;
            accC += (lane == i1) ? 1.f : 0.f;

            if (lane == 0) {
                const float s = v1 + v2 + 1e-9f;
                const size_t o = (size_t)(tok0 + t) * 2;
                float2 wo; wo.x = v1 / s; wo.y = v2 / s;
                *reinterpret_cast<float2*>(&out[o]) = wo;
                float2 io; io.x = (float)i1; io.y = (float)i2;
                *reinterpret_cast<float2*>(&out[IDX_OFF + o]) = io;
            }
        }
        ws[(size_t)blockIdx.x * 128 + lane]      = accP;
        ws[(size_t)blockIdx.x * 128 + 64 + lane] = accC;
    }
}

__global__ __launch_bounds__(256) void finalize_kernel(
    const float* __restrict__ ws, float* __restrict__ out)
{
    __shared__ float sbuf[2][4][64];
    const int tid = threadIdx.x;
    const int q   = tid >> 6;     // wave 0..3
    const int e   = tid & 63;     // expert

    float sp = 0.f, sc = 0.f;
    #pragma unroll 4
    for (int b = q; b < NBLK; b += 4) {
        sp += ws[(size_t)b * 128 + e];
        sc += ws[(size_t)b * 128 + 64 + e];
    }
    sbuf[0][q][e] = sp;
    sbuf[1][q][e] = sc;
    __syncthreads();

    if (tid < 64) {
        const float tsp = sbuf[0][0][e] + sbuf[0][1][e] + sbuf[0][2][e] + sbuf[0][3][e];
        const float tsc = sbuf[1][0][e] + sbuf[1][1][e] + sbuf[1][2][e] + sbuf[1][3][e];
        float val = (tsc * (1.0f / NUM_TOKENS)) * (tsp * (1.0f / NUM_TOKENS));
        #pragma unroll
        for (int off = 32; off >= 1; off >>= 1) val += __shfl_xor(val, off);
        if (e == 0) out[AUX_OFF] = (float)NUM_EXPERTS * val;
    }
}

extern "C" void kernel_launch(void* const* d_in, const int* in_sizes, int n_in,
                              void* d_out, int out_size, void* d_ws, size_t ws_size,
                              hipStream_t stream) {
    const float* x  = (const float*)d_in[0];
    const float* Wg = (const float*)d_in[1];
    float* out = (float*)d_out;
    float* ws  = (float*)d_ws;

    router_kernel<<<NBLK, 512, 0, stream>>>(x, Wg, out, ws);
    finalize_kernel<<<1, 256, 0, stream>>>(ws, out);
}

// Round 11
// 114.736 us; speedup vs baseline: 1.5105x; 1.5105x over previous
//
#include <hip/hip_runtime.h>
#include <math.h>

#define NUM_TOKENS 16384
#define HIDDEN 2048
#define NUM_EXPERTS 64

// out layout (fp32 flat): [0,32768) weights [t][2]; [32768,65536) indices as float; [65536] aux
#define IDX_OFF 32768
#define AUX_OFF 65536

#define TPB 32                       // tokens per block
#define NBLK (NUM_TOKENS / TPB)      // 512 blocks
#define PLANE (NUM_EXPERTS * HIDDEN) // 131072 ushorts per W term-plane

typedef __attribute__((ext_vector_type(8))) short s8v;   // bf16x8 MFMA frag (4 VGPR)
typedef __attribute__((ext_vector_type(4))) float f4v;   // fp32x4 acc frag

// ---- exact 3-term bf16 split of 8 floats (truncation; hi+mid+lo == x to 2^-24) ----
__device__ __forceinline__ void split3(const float4 a, const float4 b,
                                       s8v& vh, s8v& vm, s8v& vl) {
    const float xs[8] = {a.x, a.y, a.z, a.w, b.x, b.y, b.z, b.w};
    unsigned h[8], m[8], l[8];
    #pragma unroll
    for (int i = 0; i < 8; ++i) {
        const unsigned bb = __float_as_uint(xs[i]);
        const unsigned hh = bb & 0xffff0000u;
        const float r1 = xs[i] - __uint_as_float(hh);
        const unsigned b1 = __float_as_uint(r1);
        const unsigned mm = b1 & 0xffff0000u;
        const float r2 = r1 - __uint_as_float(mm);
        h[i] = hh; m[i] = mm; l[i] = __float_as_uint(r2);
    }
    union U { unsigned u[4]; s8v v; } uh, um, ul;
    #pragma unroll
    for (int i = 0; i < 4; ++i) {   // result = [src1.hi16 (lo), src0.hi16 (hi)]
        uh.u[i] = __builtin_amdgcn_perm(h[2*i+1], h[2*i], 0x07060302u);
        um.u[i] = __builtin_amdgcn_perm(m[2*i+1], m[2*i], 0x07060302u);
        ul.u[i] = __builtin_amdgcn_perm(l[2*i+1], l[2*i], 0x07060302u);
    }
    vh = uh.v; vm = um.v; vl = ul.v;
}

// ---- W pre-split: W[2048][64] fp32 -> WT_{hi,mid,lo}[64][2048] bf16 in ws ----
__global__ __launch_bounds__(256) void wconv_kernel(
    const float* __restrict__ Wg, unsigned short* __restrict__ wt)
{
    __shared__ float sT[64][65];
    const int tid = threadIdx.x;
    const int k0 = blockIdx.x * 64;          // 32 blocks

    #pragma unroll
    for (int i = 0; i < 4; ++i) {
        const int idx4 = i * 256 + tid;      // 0..1023 float4s
        const int k = idx4 >> 4;
        const int n4 = idx4 & 15;
        const float4 v = *reinterpret_cast<const float4*>(
            Wg + (size_t)(k0 + k) * NUM_EXPERTS + n4 * 4);
        sT[k][n4*4+0] = v.x; sT[k][n4*4+1] = v.y;
        sT[k][n4*4+2] = v.z; sT[k][n4*4+3] = v.w;
    }
    __syncthreads();

    const int n  = tid >> 2;      // expert 0..63
    const int kq = tid & 3;       // 16-k quarter of the 64-k tile
    unsigned h[16], m[16], l[16];
    #pragma unroll
    for (int j = 0; j < 16; ++j) {
        const float xv = sT[kq * 16 + j][n];
        const unsigned bb = __float_as_uint(xv);
        const unsigned hh = bb & 0xffff0000u;
        const float r1 = xv - __uint_as_float(hh);
        const unsigned b1 = __float_as_uint(r1);
        const unsigned mm = b1 & 0xffff0000u;
        const float r2 = r1 - __uint_as_float(mm);
        h[j] = hh; m[j] = mm; l[j] = __float_as_uint(r2);
    }
    uint4 ph[2], pm[2], pl[2];
    #pragma unroll
    for (int half = 0; half < 2; ++half) {
        unsigned* hp = reinterpret_cast<unsigned*>(&ph[half]);
        unsigned* mp = reinterpret_cast<unsigned*>(&pm[half]);
        unsigned* lp = reinterpret_cast<unsigned*>(&pl[half]);
        #pragma unroll
        for (int i = 0; i < 4; ++i) {
            const int j = half * 8 + 2 * i;
            hp[i] = __builtin_amdgcn_perm(h[j+1], h[j], 0x07060302u);
            mp[i] = __builtin_amdgcn_perm(m[j+1], m[j], 0x07060302u);
            lp[i] = __builtin_amdgcn_perm(l[j+1], l[j], 0x07060302u);
        }
    }
    const size_t base = (size_t)n * HIDDEN + k0 + kq * 16;   // ushort elements
    #pragma unroll
    for (int half = 0; half < 2; ++half) {
        *reinterpret_cast<uint4*>(wt + 0 * PLANE + base + half * 8) = ph[half];
        *reinterpret_cast<uint4*>(wt + 1 * PLANE + base + half * 8) = pm[half];
        *reinterpret_cast<uint4*>(wt + 2 * PLANE + base + half * 8) = pl[half];
    }
}

// ---- MFMA GEMM + epilogue. Block = 32 tokens, 4 waves = 4 K-quarters. ----
__global__ __launch_bounds__(256, 2) void gemm_kernel(
    const float* __restrict__ x, const unsigned short* __restrict__ wt,
    float* __restrict__ out, float* __restrict__ ws_aux)
{
    __shared__ float mb[3][64][32];        // k-quarter merge (24 KB)
    __shared__ float lg[TPB][68];          // logits (8.5 KB)
    __shared__ float sP[4][64], sC[4][64];

    const int tid  = threadIdx.x;
    const int q    = tid >> 6;             // k-quarter 0..3
    const int lane = tid & 63;
    const int lhi  = lane >> 4;            // k-octet 0..3
    const int llo  = lane & 15;            // frag row/col 0..15
    const int tok0 = blockIdx.x * TPB;
    const int kq0  = q * (HIDDEN / 4);     // 512 k per wave

    f4v acc[2][4];
    #pragma unroll
    for (int mf = 0; mf < 2; ++mf)
        #pragma unroll
        for (int f = 0; f < 4; ++f) acc[mf][f] = (f4v)(0.f);

    const float* xb0 = x + (size_t)(tok0 + llo) * HIDDEN + kq0 + lhi * 8;
    const float* xb1 = xb0 + (size_t)16 * HIDDEN;
    const unsigned short* wb = wt + (size_t)llo * HIDDEN + kq0 + lhi * 8;

    #pragma unroll 2
    for (int ks = 0; ks < 16; ++ks) {      // 32 k per step
        const int ko = ks * 32;
        // x fragments (fp32)
        const float4 xa0 = *reinterpret_cast<const float4*>(xb0 + ko);
        const float4 xa1 = *reinterpret_cast<const float4*>(xb0 + ko + 4);
        const float4 xc0 = *reinterpret_cast<const float4*>(xb1 + ko);
        const float4 xc1 = *reinterpret_cast<const float4*>(xb1 + ko + 4);
        // B fragments: 4 expert-frags x {hi,mid,lo}
        s8v bh[4], bm[4], bl[4];
        #pragma unroll
        for (int f = 0; f < 4; ++f) {
            const size_t o = (size_t)f * 16 * HIDDEN + ko;
            bh[f] = *reinterpret_cast<const s8v*>(wb + 0 * PLANE + o);
            bm[f] = *reinterpret_cast<const s8v*>(wb + 1 * PLANE + o);
            bl[f] = *reinterpret_cast<const s8v*>(wb + 2 * PLANE + o);
        }
        // split x in-register
        s8v ah0, am0, al0, ah1, am1, al1;
        split3(xa0, xa1, ah0, am0, al0);
        split3(xc0, xc1, ah1, am1, al1);
        // 48 MFMA: 2 M-frags x 4 N-frags x 6 term-pairs
        #pragma unroll
        for (int f = 0; f < 4; ++f) {
            acc[0][f] = __builtin_amdgcn_mfma_f32_16x16x32_bf16(ah0, bh[f], acc[0][f], 0, 0, 0);
            acc[0][f] = __builtin_amdgcn_mfma_f32_16x16x32_bf16(ah0, bm[f], acc[0][f], 0, 0, 0);
            acc[0][f] = __builtin_amdgcn_mfma_f32_16x16x32_bf16(am0, bh[f], acc[0][f], 0, 0, 0);
            acc[0][f] = __builtin_amdgcn_mfma_f32_16x16x32_bf16(ah0, bl[f], acc[0][f], 0, 0, 0);
            acc[0][f] = __builtin_amdgcn_mfma_f32_16x16x32_bf16(al0, bh[f], acc[0][f], 0, 0, 0);
            acc[0][f] = __builtin_amdgcn_mfma_f32_16x16x32_bf16(am0, bm[f], acc[0][f], 0, 0, 0);
        }
        #pragma unroll
        for (int f = 0; f < 4; ++f) {
            acc[1][f] = __builtin_amdgcn_mfma_f32_16x16x32_bf16(ah1, bh[f], acc[1][f], 0, 0, 0);
            acc[1][f] = __builtin_amdgcn_mfma_f32_16x16x32_bf16(ah1, bm[f], acc[1][f], 0, 0, 0);
            acc[1][f] = __builtin_amdgcn_mfma_f32_16x16x32_bf16(am1, bh[f], acc[1][f], 0, 0, 0);
            acc[1][f] = __builtin_amdgcn_mfma_f32_16x16x32_bf16(ah1, bl[f], acc[1][f], 0, 0, 0);
            acc[1][f] = __builtin_amdgcn_mfma_f32_16x16x32_bf16(al1, bh[f], acc[1][f], 0, 0, 0);
            acc[1][f] = __builtin_amdgcn_mfma_f32_16x16x32_bf16(am1, bm[f], acc[1][f], 0, 0, 0);
        }
    }

    // ---- k-quarter merge ----
    if (q != 0) {
        #pragma unroll
        for (int mf = 0; mf < 2; ++mf)
            #pragma unroll
            for (int f = 0; f < 4; ++f)
                *reinterpret_cast<f4v*>(&mb[q-1][lane][mf*16 + f*4]) = acc[mf][f];
    }
    __syncthreads();
    if (q == 0) {
        #pragma unroll
        for (int s = 0; s < 3; ++s)
            #pragma unroll
            for (int mf = 0; mf < 2; ++mf)
                #pragma unroll
                for (int f = 0; f < 4; ++f)
                    acc[mf][f] += *reinterpret_cast<const f4v*>(&mb[s][lane][mf*16 + f*4]);
        // logits -> LDS. C layout: col = lane&15 (expert part), row = (lane>>4)*4 + r
        #pragma unroll
        for (int mf = 0; mf < 2; ++mf)
            #pragma unroll
            for (int f = 0; f < 4; ++f)
                #pragma unroll
                for (int r = 0; r < 4; ++r)
                    lg[mf*16 + lhi*4 + r][f*16 + llo] = acc[mf][f][r];
    }
    __syncthreads();

    // ---- wave softmax + top-2 (lane = expert), wave q handles tokens q*8..+8 ----
    float accP = 0.f, accC = 0.f;
    #pragma unroll
    for (int tt = 0; tt < 8; ++tt) {
        const int t = q * 8 + tt;
        const float lv = lg[t][lane];
        float mx = lv;
        #pragma unroll
        for (int off = 32; off >= 1; off >>= 1) mx = fmaxf(mx, __shfl_xor(mx, off));
        const float p = expf(lv - mx);
        float Z = p;
        #pragma unroll
        for (int off = 32; off >= 1; off >>= 1) Z += __shfl_xor(Z, off);
        const float prob = p / Z;

        float v1 = prob; int i1 = lane;
        #pragma unroll
        for (int off = 32; off >= 1; off >>= 1) {
            const float ov = __shfl_xor(v1, off);
            const int   oi = __shfl_xor(i1, off);
            if (ov > v1 || (ov == v1 && oi < i1)) { v1 = ov; i1 = oi; }
        }
        float v2 = (lane == i1) ? -1.f : prob; int i2 = lane;
        #pragma unroll
        for (int off = 32; off >= 1; off >>= 1) {
            const float ov = __shfl_xor(v2, off);
            const int   oi = __shfl_xor(i2, off);
            if (ov > v2 || (ov == v2 && oi < i2)) { v2 = ov; i2 = oi; }
        }

        accP += prob;
        accC += (lane == i1) ? 1.f : 0.f;

        if (lane == 0) {
            const float s = v1 + v2 + 1e-9f;
            const size_t o = (size_t)(tok0 + t) * 2;
            float2 wo; wo.x = v1 / s; wo.y = v2 / s;
            *reinterpret_cast<float2*>(&out[o]) = wo;
            float2 io; io.x = (float)i1; io.y = (float)i2;
            *reinterpret_cast<float2*>(&out[IDX_OFF + o]) = io;
        }
    }

    sP[q][lane] = accP;
    sC[q][lane] = accC;
    __syncthreads();
    if (tid < 64) {
        const float sp = sP[0][tid] + sP[1][tid] + sP[2][tid] + sP[3][tid];
        const float sc = sC[0][tid] + sC[1][tid] + sC[2][tid] + sC[3][tid];
        ws_aux[(size_t)blockIdx.x * 128 + tid]      = sp;
        ws_aux[(size_t)blockIdx.x * 128 + 64 + tid] = sc;
    }
}

__global__ __launch_bounds__(256) void finalize_kernel(
    const float* __restrict__ ws_aux, float* __restrict__ out)
{
    __shared__ float sbuf[2][4][64];
    const int tid = threadIdx.x;
    const int qq  = tid >> 6;
    const int e   = tid & 63;

    float sp = 0.f, sc = 0.f;
    for (int b = qq; b < NBLK; b += 4) {
        sp += ws_aux[(size_t)b * 128 + e];
        sc += ws_aux[(size_t)b * 128 + 64 + e];
    }
    sbuf[0][qq][e] = sp;
    sbuf[1][qq][e] = sc;
    __syncthreads();

    if (tid < 64) {
        const float tsp = sbuf[0][0][e] + sbuf[0][1][e] + sbuf[0][2][e] + sbuf[0][3][e];
        const float tsc = sbuf[1][0][e] + sbuf[1][1][e] + sbuf[1][2][e] + sbuf[1][3][e];
        float val = (tsc * (1.0f / NUM_TOKENS)) * (tsp * (1.0f / NUM_TOKENS));
        #pragma unroll
        for (int off = 32; off >= 1; off >>= 1) val += __shfl_xor(val, off);
        if (e == 0) out[AUX_OFF] = (float)NUM_EXPERTS * val;
    }
}

extern "C" void kernel_launch(void* const* d_in, const int* in_sizes, int n_in,
                              void* d_out, int out_size, void* d_ws, size_t ws_size,
                              hipStream_t stream) {
    const float* x  = (const float*)d_in[0];
    const float* Wg = (const float*)d_in[1];
    float* out = (float*)d_out;
    unsigned short* wt = (unsigned short*)d_ws;
    float* ws_aux = (float*)((char*)d_ws + 3 * PLANE * sizeof(unsigned short));

    wconv_kernel<<<32, 256, 0, stream>>>(Wg, wt);
    gemm_kernel<<<NBLK, 256, 0, stream>>>(x, wt, out, ws_aux);
    finalize_kernel<<<1, 256, 0, stream>>>(ws_aux, out);
}